// Round 1
// baseline (2225.647 us; speedup 1.0000x reference)
//
#include <hip/hip_runtime.h>
#include <hip/hip_cooperative_groups.h>

namespace cg = cooperative_groups;

// HODLR matvec, fused single-launch cooperative design:
//   per level i: stage u-tile (bf16, transposed) in LDS -> proj partials ->
//   grid.sync -> reduce partials -> ts -> grid.sync -> exp from SAME LDS tile.
// u (537 MB) is read exactly ONCE from HBM (vs twice in the 3-kernel design).
// Fallback to the proven 3-kernel path if cooperative launch is refused.

typedef __attribute__((ext_vector_type(8))) short bf16x8;
typedef __attribute__((ext_vector_type(4))) float f32x4;

constexpr int BATCH = 64;
constexpr int NN    = 262144;   // 2^18 nodes
constexpr int RANK  = 64;
constexpr int DEPTH = 8;
constexpr int CHUNK = 256;      // per-wg column window (proj AND exp)
constexpr int NCHUNK = NN / CHUNK;      // 1024
constexpr int NWG  = NCHUNK;
constexpr int NTHR = 256;
constexpr int LSTR  = 264;      // legacy fallback stride
constexpr int WIN   = 256;      // legacy fallback window

__device__ __forceinline__ short f2bf(float f) {
  union { float f; unsigned u; } v; v.f = f;
  unsigned r = v.u + 0x7FFFu + ((v.u >> 16) & 1u);   // round-to-nearest-even
  return (short)(r >> 16);
}

__device__ __forceinline__ float bf2f(short s) {
  union { unsigned u; float f; } v; v.u = ((unsigned)(unsigned short)s) << 16;
  return v.f;
}

__device__ __forceinline__ bf16x8 pack8(f32x4 a, f32x4 b) {
  bf16x8 f;
  f[0] = f2bf(a[0]); f[1] = f2bf(a[1]); f[2] = f2bf(a[2]); f[3] = f2bf(a[3]);
  f[4] = f2bf(b[0]); f[5] = f2bf(b[1]); f[6] = f2bf(b[2]); f[7] = f2bf(b[3]);
  return f;
}

// LDS row offset for the transposed u-tile ulds[r][c] (shorts):
//   row r starts at r*264 + (r>>3)*8.
// - rows stay 16B-aligned (264*2=528 = 33*16; extra pad is 16B per 8 rows)
//   so proj's ds_read_b128 fragments remain legal.
// - the 8-row stride (exp's lane-group stride) = 2120 shorts = 1060 dwords
//   = 4 (mod 32) banks -> exp's scalar column reads are <=2-way (free).
__device__ __forceinline__ int rowoff(int r) { return r * 264 + ((r >> 3) << 3); }

__global__ __launch_bounds__(256, 4) void k_fused(
    const float* __restrict__ x, const float* __restrict__ diag,
    const float* __restrict__ u, float* y,
    short* part, float* ts)
{
  cg::grid_group grid = cg::this_grid();

  __shared__ alignas(16) short ulds[64 * 264 + 64];   // 33,920 B -> 4 wg/CU

  const int c0   = blockIdx.x * CHUNK;
  const int tid  = threadIdx.x;
  const int w    = tid >> 6;
  const int lane = tid & 63;
  const int lg   = lane >> 4;
  const int lr   = lane & 15;
  const int bw   = 16 * w;
  const int T    = blockIdx.x * NTHR + tid;

  // zero the atomic-accumulated ts slices (levels 0..4): 62*4096 floats.
  // Ordered before any level-0 atomicAdd by grid.sync A_0.
  if (T < 62 * 4096) ts[T] = 0.f;

  // x A-fragments (bf16), resident for all levels: lane holds
  // x[bw+lr][c0 + s*32 + lg*8 + j]
  bf16x8 xf[CHUNK / 32];
  {
    const float* xp = x + (size_t)(bw + lr) * NN + c0 + lg * 8;
    #pragma unroll
    for (int s = 0; s < CHUNK / 32; ++s) {
      f32x4 a = *(const f32x4*)(xp + s * 32);
      f32x4 b = *(const f32x4*)(xp + s * 32 + 4);
      xf[s] = pack8(a, b);
    }
  }

  // y accumulators, resident for all levels (16 c-tiles x 4 rows)
  f32x4 yacc[16];
  #pragma unroll
  for (int ct = 0; ct < 16; ++ct) yacc[ct] = (f32x4){0.f, 0.f, 0.f, 0.f};

  #pragma unroll 1
  for (int i = 0; i < DEPTH; ++i) {
    __syncthreads();   // previous level's exp LDS reads done

    // ---- stage u row (c0+tid) transposed into LDS: ulds[r][tid] ----
    {
      const float* ug = u + ((size_t)i * NN + c0 + tid) * RANK;
      #pragma unroll
      for (int h = 0; h < 4; ++h) {           // 16 floats at a time (VGPR cap)
        f32x4 t[4];
        #pragma unroll
        for (int q = 0; q < 4; ++q) t[q] = *(const f32x4*)(ug + h * 16 + q * 4);
        #pragma unroll
        for (int q = 0; q < 4; ++q) {
          #pragma unroll
          for (int e = 0; e < 4; ++e) {
            const int r = h * 16 + q * 4 + e;
            ulds[rowoff(r) + tid] = f2bf(t[q][e]);
          }
        }
      }
    }
    __syncthreads();

    // ---- proj: partial t for this chunk, one rt-quad at a time ----
    {
      short* pb = part + ((size_t)i * NCHUNK + blockIdx.x) * (BATCH * RANK);
      #pragma unroll
      for (int rt = 0; rt < 4; ++rt) {
        f32x4 pacc = (f32x4){0.f, 0.f, 0.f, 0.f};
        const int rbase = rowoff(rt * 16 + lr);
        #pragma unroll
        for (int s = 0; s < CHUNK / 32; ++s) {
          bf16x8 bf = *(const bf16x8*)&ulds[rbase + s * 32 + lg * 8];
          pacc = __builtin_amdgcn_mfma_f32_16x16x32_bf16(xf[s], bf, pacc, 0, 0, 0);
        }
        #pragma unroll
        for (int v = 0; v < 4; ++v)            // D: row = lg*4+v, col = lr
          pb[(bw + lg * 4 + v) * RANK + rt * 16 + lr] = f2bf(pacc[v]);
      }
    }

    grid.sync();   // A: all level-i partials visible

    // ---- reduce level i: part -> ts. Every thread sums exactly 16 bf16. ----
    {
      const int contrib = 512 >> i;                       // chunks per block
      const int tsbase  = ((1 << (i + 1)) - 2) * (BATCH * RANK);
      const short* pl   = part + (size_t)i * NCHUNK * (BATCH * RANK);
      if (i <= 4) {
        // entries = 2^(13+i) < nthreads: (32>>i) threads co-add one entry.
        // lanes -> consecutive e (coalesced 128B reads); grp uniform per wave.
        const int entries = 1 << (13 + i);
        const int e   = T & (entries - 1);
        const int grp = T >> (13 + i);
        const int blk = e >> 12, br = e & 4095;
        const short* p = pl + (size_t)(blk * contrib + grp * 16) * 4096 + br;
        float s = 0.f;
        #pragma unroll
        for (int k = 0; k < 16; ++k) s += bf2f(p[(size_t)k * 4096]);
        atomicAdd(&ts[tsbase + e], s);                    // device-scope
      } else {
        const int units = 1 << (i - 5);                   // 1,2,4
        for (int uu = 0; uu < units; ++uu) {
          const int e = T + (uu << 18);
          const int blk = e >> 12, br = e & 4095;
          const short* p = pl + (size_t)(blk * contrib) * 4096 + br;
          float s = 0.f;
          #pragma unroll
          for (int k = 0; k < 16; ++k)
            if (k < contrib) s += bf2f(p[(size_t)k * 4096]);
          ts[tsbase + e] = s;
        }
      }
    }

    grid.sync();   // B: level-i ts complete

    // ---- exp: yacc += U_tile @ t_sib, U read from the SAME LDS tile ----
    {
      const int blk = c0 >> (17 - i);
      const float* tb = ts + (size_t)(((1 << (i + 1)) - 2) + (blk ^ 1)) * (BATCH * RANK);

      // A fragments (t_sib): lane holds t[bw+lr][s2*32 + lg*8 + j]
      bf16x8 af[2];
      #pragma unroll
      for (int s2 = 0; s2 < 2; ++s2) {
        const float* p = tb + (size_t)(bw + lr) * RANK + s2 * 32 + lg * 8;
        af[s2] = pack8(*(const f32x4*)p, *(const f32x4*)(p + 4));
      }

      // B fragments from LDS columns: B[k=r][n=c] = u[c][r] = ulds[r][c].
      // 8x ds_read_u16 per frag; <=2-way banks by rowoff() padding.
      #pragma unroll
      for (int ct = 0; ct < 16; ++ct) {
        #pragma unroll
        for (int s2 = 0; s2 < 2; ++s2) {
          const int rb = rowoff(s2 * 32 + lg * 8);  // rows lg*8..+7 share pad group
          bf16x8 bf;
          #pragma unroll
          for (int j = 0; j < 8; ++j)
            bf[j] = ulds[rb + j * 264 + ct * 16 + lr];
          yacc[ct] = __builtin_amdgcn_mfma_f32_16x16x32_bf16(af[s2], bf, yacc[ct], 0, 0, 0);
        }
      }
    }
  }

  // ---- epilogue: y = yacc + diag*x (x re-read fp32 for exactness) ----
  // Safe vs part-aliasing: last part read is before grid.sync B_7.
  #pragma unroll
  for (int ct = 0; ct < 16; ++ct) {
    const int c = c0 + ct * 16 + lr;
    const float dg = diag[c];
    #pragma unroll
    for (int v = 0; v < 4; ++v) {
      const int b = bw + lg * 4 + v;
      const size_t idx = (size_t)b * NN + c;
      y[idx] = yacc[ct][v] + dg * x[idx];
    }
  }
}

// ================= legacy 3-kernel path (fallback only) =================

__global__ __launch_bounds__(256, 4) void k_proj2(
    const float* __restrict__ x, const float* __restrict__ u,
    short* __restrict__ part)
{
  __shared__ alignas(16) short ulds[RANK * LSTR];

  const int c0   = blockIdx.x * CHUNK;
  const int tid  = threadIdx.x;
  const int w    = tid >> 6;
  const int lane = tid & 63;
  const int lg   = lane >> 4;
  const int lr   = lane & 15;

  bf16x8 xf[CHUNK / 32];
  {
    const float* xp = x + (size_t)(16 * w + lr) * NN + c0 + lg * 8;
    #pragma unroll
    for (int s = 0; s < CHUNK / 32; ++s) {
      f32x4 a = *(const f32x4*)(xp + s * 32);
      f32x4 b = *(const f32x4*)(xp + s * 32 + 4);
      xf[s] = pack8(a, b);
    }
  }

  for (int i = 0; i < DEPTH; ++i) {
    __syncthreads();
    {
      const float* ug = u + ((size_t)i * NN + c0 + tid) * RANK;
      short* col = &ulds[tid];
      #pragma unroll
      for (int h = 0; h < 2; ++h) {
        f32x4 t[8];
        #pragma unroll
        for (int q = 0; q < 8; ++q) t[q] = *(const f32x4*)(ug + h * 32 + q * 4);
        #pragma unroll
        for (int q = 0; q < 8; ++q) {
          #pragma unroll
          for (int e = 0; e < 4; ++e)
            col[(h * 32 + q * 4 + e) * LSTR] = f2bf(t[q][e]);
        }
      }
    }
    __syncthreads();

    f32x4 pacc[4];
    #pragma unroll
    for (int rt = 0; rt < 4; ++rt) pacc[rt] = (f32x4){0.f, 0.f, 0.f, 0.f};
    #pragma unroll
    for (int s = 0; s < CHUNK / 32; ++s) {
      #pragma unroll
      for (int rt = 0; rt < 4; ++rt) {
        bf16x8 bf = *(const bf16x8*)&ulds[(rt * 16 + lr) * LSTR + s * 32 + lg * 8];
        pacc[rt] = __builtin_amdgcn_mfma_f32_16x16x32_bf16(xf[s], bf, pacc[rt], 0, 0, 0);
      }
    }

    short* pb = part + ((size_t)i * NCHUNK + blockIdx.x) * (BATCH * RANK);
    #pragma unroll
    for (int rt = 0; rt < 4; ++rt) {
      #pragma unroll
      for (int v = 0; v < 4; ++v) {
        const int b = 16 * w + lg * 4 + v;
        pb[b * RANK + rt * 16 + lr] = f2bf(pacc[rt][v]);
      }
    }
  }
}

__global__ __launch_bounds__(256, 4) void k_reduce(
    const short* __restrict__ part, float* __restrict__ ts)
{
  int g = blockIdx.x;
  int lvl = 0;
  while (g >= ((2 << lvl) * 16)) { g -= (2 << lvl) * 16; ++lvl; }
  const int block = g >> 4;
  const int bq = (g >> 2) & 3;
  const int rq = g & 3;
  const int contrib = 512 >> lvl;
  const int chunk0  = block * contrib;

  const int b = bq * 16 + (threadIdx.x >> 4);
  const int r = rq * 16 + (threadIdx.x & 15);

  const short* p = part + ((size_t)lvl * NCHUNK + chunk0) * (BATCH * RANK) + b * RANK + r;
  float s = 0.f;
  int k = 0;
  for (; k + 8 <= contrib; k += 8) {
    float a0 = bf2f(p[(size_t)(k + 0) * 4096]);
    float a1 = bf2f(p[(size_t)(k + 1) * 4096]);
    float a2 = bf2f(p[(size_t)(k + 2) * 4096]);
    float a3 = bf2f(p[(size_t)(k + 3) * 4096]);
    float a4 = bf2f(p[(size_t)(k + 4) * 4096]);
    float a5 = bf2f(p[(size_t)(k + 5) * 4096]);
    float a6 = bf2f(p[(size_t)(k + 6) * 4096]);
    float a7 = bf2f(p[(size_t)(k + 7) * 4096]);
    s += ((a0 + a1) + (a2 + a3)) + ((a4 + a5) + (a6 + a7));
  }
  for (; k < contrib; ++k) s += bf2f(p[(size_t)k * 4096]);

  const int off = (1 << (lvl + 1)) - 2;
  ts[(size_t)(off + block) * (BATCH * RANK) + b * RANK + r] = s;
}

__global__ __launch_bounds__(256, 4) void k_exp2(
    const float* __restrict__ x, const float* __restrict__ diag,
    const float* __restrict__ u, const float* __restrict__ ts,
    float* __restrict__ y)
{
  const int cw0  = blockIdx.x * WIN;
  const int tid  = threadIdx.x;
  const int w    = tid >> 6;
  const int lane = tid & 63;
  const int lg   = lane >> 4;
  const int lr   = lane & 15;
  const int bw   = 16 * w;

  f32x4 yacc[16];
  #pragma unroll
  for (int ct = 0; ct < 16; ++ct) yacc[ct] = (f32x4){0.f, 0.f, 0.f, 0.f};

  #pragma unroll
  for (int i = 0; i < DEPTH; ++i) {
    const int blk = cw0 >> (17 - i);
    const int off = (1 << (i + 1)) - 2;
    const float* tb = ts + (size_t)(off + (blk ^ 1)) * (BATCH * RANK);

    bf16x8 af[2];
    #pragma unroll
    for (int s2 = 0; s2 < 2; ++s2) {
      const float* p = tb + (size_t)(bw + lr) * RANK + s2 * 32 + lg * 8;
      af[s2] = pack8(*(const f32x4*)p, *(const f32x4*)(p + 4));
    }

    const float* ub = u + ((size_t)i * NN + cw0) * RANK;
    #pragma unroll
    for (int ct = 0; ct < 16; ++ct) {
      const float* up = ub + (size_t)(ct * 16 + lr) * RANK + lg * 8;
      #pragma unroll
      for (int s2 = 0; s2 < 2; ++s2) {
        f32x4 a = *(const f32x4*)(up + s2 * 32);
        f32x4 b = *(const f32x4*)(up + s2 * 32 + 4);
        yacc[ct] = __builtin_amdgcn_mfma_f32_16x16x32_bf16(af[s2], pack8(a, b), yacc[ct], 0, 0, 0);
      }
    }
  }

  #pragma unroll
  for (int ct = 0; ct < 16; ++ct) {
    const int c = cw0 + ct * 16 + lr;
    const float dg = diag[c];
    #pragma unroll
    for (int v = 0; v < 4; ++v) {
      const int b = bw + lg * 4 + v;
      const size_t idx = (size_t)b * NN + c;
      y[idx] = yacc[ct][v] + dg * x[idx];
    }
  }
}

extern "C" void kernel_launch(void* const* d_in, const int* in_sizes, int n_in,
                              void* d_out, int out_size, void* d_ws, size_t ws_size,
                              hipStream_t stream) {
  (void)in_sizes; (void)n_in; (void)out_size; (void)ws_size;
  const float* x    = (const float*)d_in[0];
  const float* diag = (const float*)d_in[1];
  const float* u    = (const float*)d_in[2];
  float* y    = (float*)d_out;
  short* part = (short*)d_out;          // d_out doubles as partial scratch (exact fit)
  float* ts   = (float*)d_ws;           // 8.36 MB, proven-safe ws usage

  void* args[6] = {(void*)&x, (void*)&diag, (void*)&u, (void*)&y, (void*)&part, (void*)&ts};
  if (hipLaunchCooperativeKernel((const void*)k_fused, dim3(NWG), dim3(NTHR),
                                 args, 0, stream) != hipSuccess) {
    // fallback: proven three-launch path (462 us baseline)
    k_proj2 <<<NCHUNK, 256, 0, stream>>>(x, u, part);
    k_reduce<<<8160,   256, 0, stream>>>(part, ts);
    k_exp2  <<<NN / WIN, 256, 0, stream>>>(x, diag, u, ts, y);
  }
}

// Round 2
// 1432.245 us; speedup vs baseline: 1.5540x; 1.5540x over previous
//
#include <hip/hip_runtime.h>

// HODLR matvec, fused single-launch with HAND-ROLLED grid barrier:
//   per level i: stage u-tile (bf16, transposed) in LDS -> proj partials ->
//   [bar] -> reduce partials -> ts -> [bar] -> exp from SAME LDS tile.
// u (537 MB) is read exactly ONCE from HBM. Cross-wg data (part, ts) moves
// via agent-scope (sc1) atomics -- no L2 flush/invalidate, unlike
// cg::grid.sync() which cost ~130 us/sync in round 1.
// Fallback to the proven 3-kernel path (464 us) if cooperative launch fails.

typedef __attribute__((ext_vector_type(8))) short bf16x8;
typedef __attribute__((ext_vector_type(4))) float f32x4;

constexpr int BATCH = 64;
constexpr int NN    = 262144;   // 2^18 nodes
constexpr int RANK  = 64;
constexpr int DEPTH = 8;
constexpr int CHUNK = 256;      // per-wg column window (proj AND exp)
constexpr int NCHUNK = NN / CHUNK;      // 1024
constexpr int NWG  = NCHUNK;
constexpr int NTHR = 256;
constexpr int LSTR  = 264;      // legacy fallback stride
constexpr int WIN   = 256;      // legacy fallback window
constexpr size_t TS_FLOATS = 510ull * 4096;   // 8,355,840 B of ts

__device__ __forceinline__ short f2bf(float f) {
  union { float f; unsigned u; } v; v.f = f;
  unsigned r = v.u + 0x7FFFu + ((v.u >> 16) & 1u);   // round-to-nearest-even
  return (short)(r >> 16);
}

__device__ __forceinline__ float bf2f(short s) {
  union { unsigned u; float f; } v; v.u = ((unsigned)(unsigned short)s) << 16;
  return v.f;
}

__device__ __forceinline__ bf16x8 pack8(f32x4 a, f32x4 b) {
  bf16x8 f;
  f[0] = f2bf(a[0]); f[1] = f2bf(a[1]); f[2] = f2bf(a[2]); f[3] = f2bf(a[3]);
  f[4] = f2bf(b[0]); f[5] = f2bf(b[1]); f[6] = f2bf(b[2]); f[7] = f2bf(b[3]);
  return f;
}

// LDS row offset for transposed u-tile ulds[r][c] (shorts): rows stay
// 16B-aligned (b128 legal for proj), 8-row stride = 4 mod 32 banks so
// exp's scalar column reads are <=2-way (free per m136).
__device__ __forceinline__ int rowoff(int r) { return r * 264 + ((r >> 3) << 3); }

// ---- lightweight grid barrier: monotonic agent-scope counter ----
// __syncthreads() before arrival: compiler drains vmcnt(0) per wave, so all
// agent-scope part/ts stores have reached the coherent point first.
__device__ __forceinline__ void gbar(unsigned* bar, unsigned target) {
  __syncthreads();
  if (threadIdx.x == 0) {
    __hip_atomic_fetch_add(bar, 1u, __ATOMIC_RELAXED, __HIP_MEMORY_SCOPE_AGENT);
    int it = 0;
    while (__hip_atomic_load(bar, __ATOMIC_RELAXED, __HIP_MEMORY_SCOPE_AGENT) < target) {
      if (it < 8) __builtin_amdgcn_s_sleep(2);
      else        __builtin_amdgcn_s_sleep(32);
      ++it;
    }
  }
  __syncthreads();
}

__global__ __launch_bounds__(256, 4) void k_fused2(
    const float* __restrict__ x, const float* __restrict__ diag,
    const float* __restrict__ u, float* y,
    short* part, float* ts, unsigned* bar)
{
  __shared__ alignas(16) short ulds[64 * 264 + 64];   // 33,920 B -> 4 wg/CU

  const int c0   = blockIdx.x * CHUNK;
  const int tid  = threadIdx.x;
  const int w    = tid >> 6;
  const int lane = tid & 63;
  const int lg   = lane >> 4;
  const int lr   = lane & 15;
  const int bw   = 16 * w;
  const int T    = blockIdx.x * NTHR + tid;

  // x A-fragments (bf16), resident for all levels
  bf16x8 xf[CHUNK / 32];
  {
    const float* xp = x + (size_t)(bw + lr) * NN + c0 + lg * 8;
    #pragma unroll
    for (int s = 0; s < CHUNK / 32; ++s) {
      f32x4 a = *(const f32x4*)(xp + s * 32);
      f32x4 b = *(const f32x4*)(xp + s * 32 + 4);
      xf[s] = pack8(a, b);
    }
  }

  f32x4 yacc[16];
  #pragma unroll
  for (int ct = 0; ct < 16; ++ct) yacc[ct] = (f32x4){0.f, 0.f, 0.f, 0.f};

  #pragma unroll 1
  for (int i = 0; i < DEPTH; ++i) {
    __syncthreads();   // previous level's exp LDS reads done

    // ---- stage u row (c0+tid) transposed into LDS ----
    {
      const float* ug = u + ((size_t)i * NN + c0 + tid) * RANK;
      #pragma unroll
      for (int h = 0; h < 4; ++h) {
        f32x4 t[4];
        #pragma unroll
        for (int q = 0; q < 4; ++q) t[q] = *(const f32x4*)(ug + h * 16 + q * 4);
        #pragma unroll
        for (int q = 0; q < 4; ++q) {
          #pragma unroll
          for (int e = 0; e < 4; ++e) {
            const int r = h * 16 + q * 4 + e;
            ulds[rowoff(r) + tid] = f2bf(t[q][e]);
          }
        }
      }
    }
    __syncthreads();

    // ---- proj: partial t, agent-scope (sc1) stores to part ----
    {
      unsigned short* pb = (unsigned short*)(part +
          ((size_t)i * NCHUNK + blockIdx.x) * (BATCH * RANK));
      #pragma unroll
      for (int rt = 0; rt < 4; ++rt) {
        f32x4 pacc = (f32x4){0.f, 0.f, 0.f, 0.f};
        const int rbase = rowoff(rt * 16 + lr);
        #pragma unroll
        for (int s = 0; s < CHUNK / 32; ++s) {
          bf16x8 bf = *(const bf16x8*)&ulds[rbase + s * 32 + lg * 8];
          pacc = __builtin_amdgcn_mfma_f32_16x16x32_bf16(xf[s], bf, pacc, 0, 0, 0);
        }
        #pragma unroll
        for (int v = 0; v < 4; ++v) {          // D: row = lg*4+v, col = lr
          unsigned short hv = (unsigned short)f2bf(pacc[v]);
          __hip_atomic_store(pb + (bw + lg * 4 + v) * RANK + rt * 16 + lr, hv,
                             __ATOMIC_RELAXED, __HIP_MEMORY_SCOPE_AGENT);
        }
      }
    }

    gbar(bar, (unsigned)((2 * i + 1) * NWG));   // A: level-i partials visible

    // ---- reduce level i: part -> ts (agent loads; atomic/agent stores) ----
    {
      const int contrib = 512 >> i;
      const int tsbase  = ((1 << (i + 1)) - 2) * (BATCH * RANK);
      const unsigned short* pl = (const unsigned short*)(part +
          (size_t)i * NCHUNK * (BATCH * RANK));
      if (i <= 4) {
        // entries = 2^(13+i): (32>>i) threads co-add one entry via atomicAdd.
        const int entries = 1 << (13 + i);
        const int e   = T & (entries - 1);
        const int grp = T >> (13 + i);
        const int blk = e >> 12, br = e & 4095;
        const unsigned short* p = pl + (size_t)(blk * contrib + grp * 16) * 4096 + br;
        float s = 0.f;
        #pragma unroll
        for (int k = 0; k < 16; ++k) {
          unsigned short h = __hip_atomic_load(p + (size_t)k * 4096,
                                               __ATOMIC_RELAXED, __HIP_MEMORY_SCOPE_AGENT);
          s += bf2f((short)h);
        }
        atomicAdd(&ts[tsbase + e], s);          // device-scope, coherent point
      } else {
        const int units = 1 << (i - 5);         // 1,2,4
        for (int uu = 0; uu < units; ++uu) {
          const int e = T + (uu << 18);
          const int blk = e >> 12, br = e & 4095;
          const unsigned short* p = pl + (size_t)(blk * contrib) * 4096 + br;
          float s = 0.f;
          #pragma unroll
          for (int k = 0; k < 16; ++k) {
            if (k < contrib) {
              unsigned short h = __hip_atomic_load(p + (size_t)k * 4096,
                                                   __ATOMIC_RELAXED, __HIP_MEMORY_SCOPE_AGENT);
              s += bf2f((short)h);
            }
          }
          __hip_atomic_store(&ts[tsbase + e], s,
                             __ATOMIC_RELAXED, __HIP_MEMORY_SCOPE_AGENT);
        }
      }
    }

    gbar(bar, (unsigned)((2 * i + 2) * NWG));   // B: level-i ts complete

    // ---- exp: yacc += U_tile @ t_sib, U from the SAME LDS tile ----
    {
      const int blk = c0 >> (17 - i);
      const float* tb = ts + (size_t)(((1 << (i + 1)) - 2) + (blk ^ 1)) * (BATCH * RANK);

      bf16x8 af[2];
      #pragma unroll
      for (int s2 = 0; s2 < 2; ++s2) {
        const float* p = tb + (size_t)(bw + lr) * RANK + s2 * 32 + lg * 8;
        f32x4 a, b;
        #pragma unroll
        for (int j = 0; j < 4; ++j) {
          a[j] = __hip_atomic_load(p + j,     __ATOMIC_RELAXED, __HIP_MEMORY_SCOPE_AGENT);
          b[j] = __hip_atomic_load(p + 4 + j, __ATOMIC_RELAXED, __HIP_MEMORY_SCOPE_AGENT);
        }
        af[s2] = pack8(a, b);
      }

      #pragma unroll
      for (int ct = 0; ct < 16; ++ct) {
        #pragma unroll
        for (int s2 = 0; s2 < 2; ++s2) {
          const int rb = rowoff(s2 * 32 + lg * 8);
          bf16x8 bf;
          #pragma unroll
          for (int j = 0; j < 8; ++j)
            bf[j] = ulds[rb + j * 264 + ct * 16 + lr];
          yacc[ct] = __builtin_amdgcn_mfma_f32_16x16x32_bf16(af[s2], bf, yacc[ct], 0, 0, 0);
        }
      }
    }
  }

  // ---- epilogue: y = yacc + diag*x ----
  // Safe vs part-aliasing: last part read is before barrier 16.
  #pragma unroll
  for (int ct = 0; ct < 16; ++ct) {
    const int c = c0 + ct * 16 + lr;
    const float dg = diag[c];
    #pragma unroll
    for (int v = 0; v < 4; ++v) {
      const int b = bw + lg * 4 + v;
      const size_t idx = (size_t)b * NN + c;
      y[idx] = yacc[ct][v] + dg * x[idx];
    }
  }
}

// ================= legacy 3-kernel path (fallback only, proven 464 us) ======

__global__ __launch_bounds__(256, 4) void k_proj2(
    const float* __restrict__ x, const float* __restrict__ u,
    short* __restrict__ part)
{
  __shared__ alignas(16) short ulds[RANK * LSTR];

  const int c0   = blockIdx.x * CHUNK;
  const int tid  = threadIdx.x;
  const int w    = tid >> 6;
  const int lane = tid & 63;
  const int lg   = lane >> 4;
  const int lr   = lane & 15;

  bf16x8 xf[CHUNK / 32];
  {
    const float* xp = x + (size_t)(16 * w + lr) * NN + c0 + lg * 8;
    #pragma unroll
    for (int s = 0; s < CHUNK / 32; ++s) {
      f32x4 a = *(const f32x4*)(xp + s * 32);
      f32x4 b = *(const f32x4*)(xp + s * 32 + 4);
      xf[s] = pack8(a, b);
    }
  }

  for (int i = 0; i < DEPTH; ++i) {
    __syncthreads();
    {
      const float* ug = u + ((size_t)i * NN + c0 + tid) * RANK;
      short* col = &ulds[tid];
      #pragma unroll
      for (int h = 0; h < 2; ++h) {
        f32x4 t[8];
        #pragma unroll
        for (int q = 0; q < 8; ++q) t[q] = *(const f32x4*)(ug + h * 32 + q * 4);
        #pragma unroll
        for (int q = 0; q < 8; ++q) {
          #pragma unroll
          for (int e = 0; e < 4; ++e)
            col[(h * 32 + q * 4 + e) * LSTR] = f2bf(t[q][e]);
        }
      }
    }
    __syncthreads();

    f32x4 pacc[4];
    #pragma unroll
    for (int rt = 0; rt < 4; ++rt) pacc[rt] = (f32x4){0.f, 0.f, 0.f, 0.f};
    #pragma unroll
    for (int s = 0; s < CHUNK / 32; ++s) {
      #pragma unroll
      for (int rt = 0; rt < 4; ++rt) {
        bf16x8 bf = *(const bf16x8*)&ulds[(rt * 16 + lr) * LSTR + s * 32 + lg * 8];
        pacc[rt] = __builtin_amdgcn_mfma_f32_16x16x32_bf16(xf[s], bf, pacc[rt], 0, 0, 0);
      }
    }

    short* pb = part + ((size_t)i * NCHUNK + blockIdx.x) * (BATCH * RANK);
    #pragma unroll
    for (int rt = 0; rt < 4; ++rt) {
      #pragma unroll
      for (int v = 0; v < 4; ++v) {
        const int b = 16 * w + lg * 4 + v;
        pb[b * RANK + rt * 16 + lr] = f2bf(pacc[rt][v]);
      }
    }
  }
}

__global__ __launch_bounds__(256, 4) void k_reduce(
    const short* __restrict__ part, float* __restrict__ ts)
{
  int g = blockIdx.x;
  int lvl = 0;
  while (g >= ((2 << lvl) * 16)) { g -= (2 << lvl) * 16; ++lvl; }
  const int block = g >> 4;
  const int bq = (g >> 2) & 3;
  const int rq = g & 3;
  const int contrib = 512 >> lvl;
  const int chunk0  = block * contrib;

  const int b = bq * 16 + (threadIdx.x >> 4);
  const int r = rq * 16 + (threadIdx.x & 15);

  const short* p = part + ((size_t)lvl * NCHUNK + chunk0) * (BATCH * RANK) + b * RANK + r;
  float s = 0.f;
  int k = 0;
  for (; k + 8 <= contrib; k += 8) {
    float a0 = bf2f(p[(size_t)(k + 0) * 4096]);
    float a1 = bf2f(p[(size_t)(k + 1) * 4096]);
    float a2 = bf2f(p[(size_t)(k + 2) * 4096]);
    float a3 = bf2f(p[(size_t)(k + 3) * 4096]);
    float a4 = bf2f(p[(size_t)(k + 4) * 4096]);
    float a5 = bf2f(p[(size_t)(k + 5) * 4096]);
    float a6 = bf2f(p[(size_t)(k + 6) * 4096]);
    float a7 = bf2f(p[(size_t)(k + 7) * 4096]);
    s += ((a0 + a1) + (a2 + a3)) + ((a4 + a5) + (a6 + a7));
  }
  for (; k < contrib; ++k) s += bf2f(p[(size_t)k * 4096]);

  const int off = (1 << (lvl + 1)) - 2;
  ts[(size_t)(off + block) * (BATCH * RANK) + b * RANK + r] = s;
}

__global__ __launch_bounds__(256, 4) void k_exp2(
    const float* __restrict__ x, const float* __restrict__ diag,
    const float* __restrict__ u, const float* __restrict__ ts,
    float* __restrict__ y)
{
  const int cw0  = blockIdx.x * WIN;
  const int tid  = threadIdx.x;
  const int w    = tid >> 6;
  const int lane = tid & 63;
  const int lg   = lane >> 4;
  const int lr   = lane & 15;
  const int bw   = 16 * w;

  f32x4 yacc[16];
  #pragma unroll
  for (int ct = 0; ct < 16; ++ct) yacc[ct] = (f32x4){0.f, 0.f, 0.f, 0.f};

  #pragma unroll
  for (int i = 0; i < DEPTH; ++i) {
    const int blk = cw0 >> (17 - i);
    const int off = (1 << (i + 1)) - 2;
    const float* tb = ts + (size_t)(off + (blk ^ 1)) * (BATCH * RANK);

    bf16x8 af[2];
    #pragma unroll
    for (int s2 = 0; s2 < 2; ++s2) {
      const float* p = tb + (size_t)(bw + lr) * RANK + s2 * 32 + lg * 8;
      af[s2] = pack8(*(const f32x4*)p, *(const f32x4*)(p + 4));
    }

    const float* ub = u + ((size_t)i * NN + cw0) * RANK;
    #pragma unroll
    for (int ct = 0; ct < 16; ++ct) {
      const float* up = ub + (size_t)(ct * 16 + lr) * RANK + lg * 8;
      #pragma unroll
      for (int s2 = 0; s2 < 2; ++s2) {
        f32x4 a = *(const f32x4*)(up + s2 * 32);
        f32x4 b = *(const f32x4*)(up + s2 * 32 + 4);
        yacc[ct] = __builtin_amdgcn_mfma_f32_16x16x32_bf16(af[s2], pack8(a, b), yacc[ct], 0, 0, 0);
      }
    }
  }

  #pragma unroll
  for (int ct = 0; ct < 16; ++ct) {
    const int c = cw0 + ct * 16 + lr;
    const float dg = diag[c];
    #pragma unroll
    for (int v = 0; v < 4; ++v) {
      const int b = bw + lg * 4 + v;
      const size_t idx = (size_t)b * NN + c;
      y[idx] = yacc[ct][v] + dg * x[idx];
    }
  }
}

extern "C" void kernel_launch(void* const* d_in, const int* in_sizes, int n_in,
                              void* d_out, int out_size, void* d_ws, size_t ws_size,
                              hipStream_t stream) {
  (void)in_sizes; (void)n_in; (void)out_size; (void)ws_size;
  const float* x    = (const float*)d_in[0];
  const float* diag = (const float*)d_in[1];
  const float* u    = (const float*)d_in[2];
  float* y    = (float*)d_out;
  short* part = (short*)d_out;          // d_out doubles as partial scratch
  float* ts   = (float*)d_ws;
  unsigned* bar = (unsigned*)(ts + TS_FLOATS);   // one counter, own cacheline

  // zero ts (atomic-accumulated) + barrier counter; graph-capturable
  hipMemsetAsync(d_ws, 0, TS_FLOATS * 4 + 64, stream);

  void* args[7] = {(void*)&x, (void*)&diag, (void*)&u, (void*)&y,
                   (void*)&part, (void*)&ts, (void*)&bar};
  if (hipLaunchCooperativeKernel((const void*)k_fused2, dim3(NWG), dim3(NTHR),
                                 args, 0, stream) != hipSuccess) {
    // fallback: proven three-launch path (464 us baseline)
    k_proj2 <<<NCHUNK, 256, 0, stream>>>(x, u, part);
    k_reduce<<<8160,   256, 0, stream>>>(part, ts);
    k_exp2  <<<NN / WIN, 256, 0, stream>>>(x, diag, u, ts, y);
  }
}

// Round 3
// 488.609 us; speedup vs baseline: 4.5551x; 2.9313x over previous
//
#include <hip/hip_runtime.h>

// HODLR matvec, fused single-launch, round 3:
//   - distributed grid barrier: 64 arrival lines (16 wgs each), wg0 wave-0
//     polls all lines lane-parallel, 64 release lines (<=15 pollers each).
//     Kills the 1024-on-one-line atomic/poll serialization (~67us/barrier in r2).
//   - atomic-free reduce: levels 0-2 two-stage plain stores (+1 barrier each),
//     levels 3-4 one-thread-per-entry, levels 5-7 as before. No ts memset.
// u (537 MB) still read exactly once. Phase code (stage/proj/exp) unchanged.
// Fallback to the proven 3-kernel path (464 us) if cooperative launch fails.

typedef __attribute__((ext_vector_type(8))) short bf16x8;
typedef __attribute__((ext_vector_type(4))) float f32x4;

constexpr int BATCH = 64;
constexpr int NN    = 262144;   // 2^18 nodes
constexpr int RANK  = 64;
constexpr int DEPTH = 8;
constexpr int CHUNK = 256;      // per-wg column window (proj AND exp)
constexpr int NCHUNK = NN / CHUNK;      // 1024
constexpr int NWG  = NCHUNK;
constexpr int NTHR = 256;
constexpr int LSTR  = 264;      // legacy fallback stride
constexpr int WIN   = 256;      // legacy fallback window
constexpr size_t TS_FLOATS = 510ull * 4096;   // 8,355,840 B of ts
constexpr int BARSTRIDE = 256;  // dwords between barrier lines (1 KB)

__device__ __forceinline__ short f2bf(float f) {
  union { float f; unsigned u; } v; v.f = f;
  unsigned r = v.u + 0x7FFFu + ((v.u >> 16) & 1u);   // round-to-nearest-even
  return (short)(r >> 16);
}

__device__ __forceinline__ float bf2f(short s) {
  union { unsigned u; float f; } v; v.u = ((unsigned)(unsigned short)s) << 16;
  return v.f;
}

__device__ __forceinline__ bf16x8 pack8(f32x4 a, f32x4 b) {
  bf16x8 f;
  f[0] = f2bf(a[0]); f[1] = f2bf(a[1]); f[2] = f2bf(a[2]); f[3] = f2bf(a[3]);
  f[4] = f2bf(b[0]); f[5] = f2bf(b[1]); f[6] = f2bf(b[2]); f[7] = f2bf(b[3]);
  return f;
}

// agent-scope (XCD-L2-bypassing) access helpers
__device__ __forceinline__ unsigned short aload_u16(const unsigned short* p) {
  return __hip_atomic_load(p, __ATOMIC_RELAXED, __HIP_MEMORY_SCOPE_AGENT);
}
__device__ __forceinline__ float aload_f32(const float* p) {
  return __hip_atomic_load(p, __ATOMIC_RELAXED, __HIP_MEMORY_SCOPE_AGENT);
}
__device__ __forceinline__ void astore_u16(unsigned short* p, unsigned short v) {
  __hip_atomic_store(p, v, __ATOMIC_RELAXED, __HIP_MEMORY_SCOPE_AGENT);
}
__device__ __forceinline__ void astore_f32(float* p, float v) {
  __hip_atomic_store(p, v, __ATOMIC_RELAXED, __HIP_MEMORY_SCOPE_AGENT);
}

// LDS row offset for transposed u-tile ulds[r][c] (shorts): rows stay
// 16B-aligned (b128 legal for proj), 8-row stride = 4 mod 32 banks so
// exp's scalar column reads are <=2-way (free per m136).
__device__ __forceinline__ int rowoff(int r) { return r * 264 + ((r >> 3) << 3); }

// ---- distributed grid barrier ----
// bars[l*BARSTRIDE],        l<64 : arrival counters (16 wgs per line)
// bars[(64+l)*BARSTRIDE],   l<64 : release flags (phase number)
// wg0 wave-0 detects arrivals lane-parallel (1 poller per line), then 64
// lanes store the release phase in one instruction (<=15 pollers per line).
// __syncthreads() on entry drains vmcnt -> all agent stores acked first.
__device__ __forceinline__ void gbar3(unsigned* bars, unsigned ph) {
  __syncthreads();
  const int tid = threadIdx.x;
  if (blockIdx.x == 0) {
    if (tid == 0)
      __hip_atomic_fetch_add(bars, 1u, __ATOMIC_RELAXED, __HIP_MEMORY_SCOPE_AGENT);
    if (tid < 64) {
      unsigned* a = bars + tid * BARSTRIDE;
      while (__hip_atomic_load(a, __ATOMIC_RELAXED, __HIP_MEMORY_SCOPE_AGENT) < ph * 16u)
        __builtin_amdgcn_s_sleep(1);
    }
    __syncthreads();   // all 64 lines observed complete
    if (tid < 64)
      __hip_atomic_store(bars + (64 + tid) * BARSTRIDE, ph,
                         __ATOMIC_RELAXED, __HIP_MEMORY_SCOPE_AGENT);
    __syncthreads();
  } else {
    if (tid == 0) {
      __hip_atomic_fetch_add(bars + (blockIdx.x & 63) * BARSTRIDE, 1u,
                             __ATOMIC_RELAXED, __HIP_MEMORY_SCOPE_AGENT);
      unsigned* r = bars + (64 + (blockIdx.x & 63)) * BARSTRIDE;
      while (__hip_atomic_load(r, __ATOMIC_RELAXED, __HIP_MEMORY_SCOPE_AGENT) < ph)
        __builtin_amdgcn_s_sleep(4);
    }
    __syncthreads();
  }
}

__global__ __launch_bounds__(256, 4) void k_fused3(
    const float* __restrict__ x, const float* __restrict__ diag,
    const float* __restrict__ u, float* y,
    short* part, float* ts, unsigned* bars, float* s1)
{
  __shared__ alignas(16) short ulds[64 * 264 + 64];   // 33,920 B -> 4 wg/CU

  const int c0   = blockIdx.x * CHUNK;
  const int tid  = threadIdx.x;
  const int w    = tid >> 6;
  const int lane = tid & 63;
  const int lg   = lane >> 4;
  const int lr   = lane & 15;
  const int bw   = 16 * w;
  const int T    = blockIdx.x * NTHR + tid;

  // x A-fragments (bf16), resident for all levels
  bf16x8 xf[CHUNK / 32];
  {
    const float* xp = x + (size_t)(bw + lr) * NN + c0 + lg * 8;
    #pragma unroll
    for (int s = 0; s < CHUNK / 32; ++s) {
      f32x4 a = *(const f32x4*)(xp + s * 32);
      f32x4 b = *(const f32x4*)(xp + s * 32 + 4);
      xf[s] = pack8(a, b);
    }
  }

  f32x4 yacc[16];
  #pragma unroll
  for (int ct = 0; ct < 16; ++ct) yacc[ct] = (f32x4){0.f, 0.f, 0.f, 0.f};

  unsigned ph = 0;

  #pragma unroll 1
  for (int i = 0; i < DEPTH; ++i) {
    __syncthreads();   // previous level's exp LDS reads done

    // ---- stage u row (c0+tid) transposed into LDS ----
    {
      const float* ug = u + ((size_t)i * NN + c0 + tid) * RANK;
      #pragma unroll
      for (int h = 0; h < 4; ++h) {
        f32x4 t[4];
        #pragma unroll
        for (int q = 0; q < 4; ++q) t[q] = *(const f32x4*)(ug + h * 16 + q * 4);
        #pragma unroll
        for (int q = 0; q < 4; ++q) {
          #pragma unroll
          for (int e = 0; e < 4; ++e) {
            const int r = h * 16 + q * 4 + e;
            ulds[rowoff(r) + tid] = f2bf(t[q][e]);
          }
        }
      }
    }
    __syncthreads();

    // ---- proj: partial t, agent-scope stores to part ----
    {
      unsigned short* pb = (unsigned short*)(part +
          ((size_t)i * NCHUNK + blockIdx.x) * (BATCH * RANK));
      #pragma unroll
      for (int rt = 0; rt < 4; ++rt) {
        f32x4 pacc = (f32x4){0.f, 0.f, 0.f, 0.f};
        const int rbase = rowoff(rt * 16 + lr);
        #pragma unroll
        for (int s = 0; s < CHUNK / 32; ++s) {
          bf16x8 bf = *(const bf16x8*)&ulds[rbase + s * 32 + lg * 8];
          pacc = __builtin_amdgcn_mfma_f32_16x16x32_bf16(xf[s], bf, pacc, 0, 0, 0);
        }
        #pragma unroll
        for (int v = 0; v < 4; ++v)            // D: row = lg*4+v, col = lr
          astore_u16(pb + (bw + lg * 4 + v) * RANK + rt * 16 + lr,
                     (unsigned short)f2bf(pacc[v]));
      }
    }

    gbar3(bars, ++ph);   // A: level-i partials visible

    // ---- reduce level i: part -> ts, no atomics ----
    {
      const int contrib = 512 >> i;
      const int tsbase  = ((1 << (i + 1)) - 2) * (BATCH * RANK);
      const unsigned short* pl = (const unsigned short*)(part +
          (size_t)i * NCHUNK * (BATCH * RANK));
      if (i <= 2) {
        // stage 1: every thread sums 16 chunk-partials of one (grp, e)
        const int entries = 1 << (13 + i);     // 8192, 16384, 32768
        const int G       = 32 >> i;           // 32, 16, 8
        const int e   = T & (entries - 1);
        const int grp = T >> (13 + i);
        const int blk = e >> 12, br = e & 4095;
        const unsigned short* p = pl + (size_t)(blk * contrib + grp * 16) * 4096 + br;
        float s = 0.f;
        #pragma unroll
        for (int k = 0; k < 16; ++k) s += bf2f((short)aload_u16(p + (size_t)k * 4096));
        astore_f32(&s1[(size_t)grp * entries + e], s);

        gbar3(bars, ++ph);   // A2: stage-1 sums visible

        // stage 2: one thread per entry sums G group-partials
        if (T < entries) {
          float s2 = 0.f;
          #pragma unroll 8
          for (int g2 = 0; g2 < G; ++g2)
            s2 += aload_f32(&s1[(size_t)g2 * entries + T]);
          astore_f32(&ts[tsbase + T], s2);
        }
      } else if (i <= 4) {
        // one thread per entry, contrib = 64 / 32 loads, no collisions
        const int entries = 1 << (13 + i);     // 65536, 131072
        if (T < entries) {
          const int blk = T >> 12, br = T & 4095;
          const unsigned short* p = pl + (size_t)(blk * contrib) * 4096 + br;
          float s = 0.f;
          for (int k0 = 0; k0 < contrib; k0 += 16) {
            #pragma unroll
            for (int k = 0; k < 16; ++k)
              s += bf2f((short)aload_u16(p + (size_t)(k0 + k) * 4096));
          }
          astore_f32(&ts[tsbase + T], s);
        }
      } else {
        const int units = 1 << (i - 5);        // 1, 2, 4
        for (int uu = 0; uu < units; ++uu) {
          const int e = T + (uu << 18);
          const int blk = e >> 12, br = e & 4095;
          const unsigned short* p = pl + (size_t)(blk * contrib) * 4096 + br;
          float s = 0.f;
          #pragma unroll
          for (int k = 0; k < 16; ++k)
            if (k < contrib) s += bf2f((short)aload_u16(p + (size_t)k * 4096));
          astore_f32(&ts[tsbase + e], s);
        }
      }
    }

    gbar3(bars, ++ph);   // B: level-i ts complete

    // ---- exp: yacc += U_tile @ t_sib, U from the SAME LDS tile ----
    {
      const int blk = c0 >> (17 - i);
      const float* tb = ts + (size_t)(((1 << (i + 1)) - 2) + (blk ^ 1)) * (BATCH * RANK);

      bf16x8 af[2];
      #pragma unroll
      for (int s2 = 0; s2 < 2; ++s2) {
        const float* p = tb + (size_t)(bw + lr) * RANK + s2 * 32 + lg * 8;
        f32x4 a, b;
        #pragma unroll
        for (int j = 0; j < 4; ++j) {
          a[j] = aload_f32(p + j);
          b[j] = aload_f32(p + 4 + j);
        }
        af[s2] = pack8(a, b);
      }

      #pragma unroll
      for (int ct = 0; ct < 16; ++ct) {
        #pragma unroll
        for (int s2 = 0; s2 < 2; ++s2) {
          const int rb = rowoff(s2 * 32 + lg * 8);
          bf16x8 bf;
          #pragma unroll
          for (int j = 0; j < 8; ++j)
            bf[j] = ulds[rb + j * 264 + ct * 16 + lr];
          yacc[ct] = __builtin_amdgcn_mfma_f32_16x16x32_bf16(af[s2], bf, yacc[ct], 0, 0, 0);
        }
      }
    }
  }

  // ---- epilogue: y = yacc + diag*x ----
  // Safe vs part-aliasing: last part read is before the final barrier.
  #pragma unroll
  for (int ct = 0; ct < 16; ++ct) {
    const int c = c0 + ct * 16 + lr;
    const float dg = diag[c];
    #pragma unroll
    for (int v = 0; v < 4; ++v) {
      const int b = bw + lg * 4 + v;
      const size_t idx = (size_t)b * NN + c;
      y[idx] = yacc[ct][v] + dg * x[idx];
    }
  }
}

// ================= legacy 3-kernel path (fallback only, proven 464 us) ======

__global__ __launch_bounds__(256, 4) void k_proj2(
    const float* __restrict__ x, const float* __restrict__ u,
    short* __restrict__ part)
{
  __shared__ alignas(16) short ulds[RANK * LSTR];

  const int c0   = blockIdx.x * CHUNK;
  const int tid  = threadIdx.x;
  const int w    = tid >> 6;
  const int lane = tid & 63;
  const int lg   = lane >> 4;
  const int lr   = lane & 15;

  bf16x8 xf[CHUNK / 32];
  {
    const float* xp = x + (size_t)(16 * w + lr) * NN + c0 + lg * 8;
    #pragma unroll
    for (int s = 0; s < CHUNK / 32; ++s) {
      f32x4 a = *(const f32x4*)(xp + s * 32);
      f32x4 b = *(const f32x4*)(xp + s * 32 + 4);
      xf[s] = pack8(a, b);
    }
  }

  for (int i = 0; i < DEPTH; ++i) {
    __syncthreads();
    {
      const float* ug = u + ((size_t)i * NN + c0 + tid) * RANK;
      short* col = &ulds[tid];
      #pragma unroll
      for (int h = 0; h < 2; ++h) {
        f32x4 t[8];
        #pragma unroll
        for (int q = 0; q < 8; ++q) t[q] = *(const f32x4*)(ug + h * 32 + q * 4);
        #pragma unroll
        for (int q = 0; q < 8; ++q) {
          #pragma unroll
          for (int e = 0; e < 4; ++e)
            col[(h * 32 + q * 4 + e) * LSTR] = f2bf(t[q][e]);
        }
      }
    }
    __syncthreads();

    f32x4 pacc[4];
    #pragma unroll
    for (int rt = 0; rt < 4; ++rt) pacc[rt] = (f32x4){0.f, 0.f, 0.f, 0.f};
    #pragma unroll
    for (int s = 0; s < CHUNK / 32; ++s) {
      #pragma unroll
      for (int rt = 0; rt < 4; ++rt) {
        bf16x8 bf = *(const bf16x8*)&ulds[(rt * 16 + lr) * LSTR + s * 32 + lg * 8];
        pacc[rt] = __builtin_amdgcn_mfma_f32_16x16x32_bf16(xf[s], bf, pacc[rt], 0, 0, 0);
      }
    }

    short* pb = part + ((size_t)i * NCHUNK + blockIdx.x) * (BATCH * RANK);
    #pragma unroll
    for (int rt = 0; rt < 4; ++rt) {
      #pragma unroll
      for (int v = 0; v < 4; ++v) {
        const int b = 16 * w + lg * 4 + v;
        pb[b * RANK + rt * 16 + lr] = f2bf(pacc[rt][v]);
      }
    }
  }
}

__global__ __launch_bounds__(256, 4) void k_reduce(
    const short* __restrict__ part, float* __restrict__ ts)
{
  int g = blockIdx.x;
  int lvl = 0;
  while (g >= ((2 << lvl) * 16)) { g -= (2 << lvl) * 16; ++lvl; }
  const int block = g >> 4;
  const int bq = (g >> 2) & 3;
  const int rq = g & 3;
  const int contrib = 512 >> lvl;
  const int chunk0  = block * contrib;

  const int b = bq * 16 + (threadIdx.x >> 4);
  const int r = rq * 16 + (threadIdx.x & 15);

  const short* p = part + ((size_t)lvl * NCHUNK + chunk0) * (BATCH * RANK) + b * RANK + r;
  float s = 0.f;
  int k = 0;
  for (; k + 8 <= contrib; k += 8) {
    float a0 = bf2f(p[(size_t)(k + 0) * 4096]);
    float a1 = bf2f(p[(size_t)(k + 1) * 4096]);
    float a2 = bf2f(p[(size_t)(k + 2) * 4096]);
    float a3 = bf2f(p[(size_t)(k + 3) * 4096]);
    float a4 = bf2f(p[(size_t)(k + 4) * 4096]);
    float a5 = bf2f(p[(size_t)(k + 5) * 4096]);
    float a6 = bf2f(p[(size_t)(k + 6) * 4096]);
    float a7 = bf2f(p[(size_t)(k + 7) * 4096]);
    s += ((a0 + a1) + (a2 + a3)) + ((a4 + a5) + (a6 + a7));
  }
  for (; k < contrib; ++k) s += bf2f(p[(size_t)k * 4096]);

  const int off = (1 << (lvl + 1)) - 2;
  ts[(size_t)(off + block) * (BATCH * RANK) + b * RANK + r] = s;
}

__global__ __launch_bounds__(256, 4) void k_exp2(
    const float* __restrict__ x, const float* __restrict__ diag,
    const float* __restrict__ u, const float* __restrict__ ts,
    float* __restrict__ y)
{
  const int cw0  = blockIdx.x * WIN;
  const int tid  = threadIdx.x;
  const int w    = tid >> 6;
  const int lane = tid & 63;
  const int lg   = lane >> 4;
  const int lr   = lane & 15;
  const int bw   = 16 * w;

  f32x4 yacc[16];
  #pragma unroll
  for (int ct = 0; ct < 16; ++ct) yacc[ct] = (f32x4){0.f, 0.f, 0.f, 0.f};

  #pragma unroll
  for (int i = 0; i < DEPTH; ++i) {
    const int blk = cw0 >> (17 - i);
    const int off = (1 << (i + 1)) - 2;
    const float* tb = ts + (size_t)(off + (blk ^ 1)) * (BATCH * RANK);

    bf16x8 af[2];
    #pragma unroll
    for (int s2 = 0; s2 < 2; ++s2) {
      const float* p = tb + (size_t)(bw + lr) * RANK + s2 * 32 + lg * 8;
      af[s2] = pack8(*(const f32x4*)p, *(const f32x4*)(p + 4));
    }

    const float* ub = u + ((size_t)i * NN + cw0) * RANK;
    #pragma unroll
    for (int ct = 0; ct < 16; ++ct) {
      const float* up = ub + (size_t)(ct * 16 + lr) * RANK + lg * 8;
      #pragma unroll
      for (int s2 = 0; s2 < 2; ++s2) {
        f32x4 a = *(const f32x4*)(up + s2 * 32);
        f32x4 b = *(const f32x4*)(up + s2 * 32 + 4);
        yacc[ct] = __builtin_amdgcn_mfma_f32_16x16x32_bf16(af[s2], pack8(a, b), yacc[ct], 0, 0, 0);
      }
    }
  }

  #pragma unroll
  for (int ct = 0; ct < 16; ++ct) {
    const int c = cw0 + ct * 16 + lr;
    const float dg = diag[c];
    #pragma unroll
    for (int v = 0; v < 4; ++v) {
      const int b = bw + lg * 4 + v;
      const size_t idx = (size_t)b * NN + c;
      y[idx] = yacc[ct][v] + dg * x[idx];
    }
  }
}

extern "C" void kernel_launch(void* const* d_in, const int* in_sizes, int n_in,
                              void* d_out, int out_size, void* d_ws, size_t ws_size,
                              hipStream_t stream) {
  (void)in_sizes; (void)n_in; (void)out_size; (void)ws_size;
  const float* x    = (const float*)d_in[0];
  const float* diag = (const float*)d_in[1];
  const float* u    = (const float*)d_in[2];
  float* y    = (float*)d_out;
  short* part = (short*)d_out;          // d_out doubles as partial scratch
  float* ts   = (float*)d_ws;

  // ws layout: ts (8,355,840 B) | bars (128 lines * 1 KB = 131,072 B) | s1 (1 MB)
  char* wsb = (char*)d_ws;
  unsigned* bars = (unsigned*)(wsb + TS_FLOATS * 4);
  float*    s1   = (float*)(wsb + TS_FLOATS * 4 + 128 * BARSTRIDE * 4);

  // zero only the barrier region (ts is fully overwritten by plain stores now)
  hipMemsetAsync(wsb + TS_FLOATS * 4, 0, 128 * BARSTRIDE * 4, stream);

  void* args[8] = {(void*)&x, (void*)&diag, (void*)&u, (void*)&y,
                   (void*)&part, (void*)&ts, (void*)&bars, (void*)&s1};
  if (hipLaunchCooperativeKernel((const void*)k_fused3, dim3(NWG), dim3(NTHR),
                                 args, 0, stream) != hipSuccess) {
    // fallback: proven three-launch path (464 us baseline)
    k_proj2 <<<NCHUNK, 256, 0, stream>>>(x, u, part);
    k_reduce<<<8160,   256, 0, stream>>>(part, ts);
    k_exp2  <<<NN / WIN, 256, 0, stream>>>(x, diag, u, ts, y);
  }
}